// Round 1
// baseline (437.551 us; speedup 1.0000x reference)
//
#include <hip/hip_runtime.h>
#include <math.h>

// Soft decision-tree ensemble forward.
// x: [B=1024, T=16, D=10, W=512] fp32 flat. out: [B, T] fp32.
// One wave (64 lanes) per (b,t). Lane j owns elements [8j, 8j+8) of each row.
//
// Persistent-wave software-pipelined version: 4096 waves, each streaming
// ITERS=4 (b,t) pairs. At every compute point 8-20 global loads remain in
// flight (P2(k) issued before S-compute of P1(k); P1(k+1) issued before the
// fold/butterfly of pair k), so the butterfly's dependent shuffle chain no
// longer drains the memory pipe. Math is bit-identical to the verified
// single-pair kernel (absmax 0.0).

#define NUM_TREES 16
#define DEPTH     10
#define WIDTH     512
#define BATCH     1024

#define PAIRS_TOTAL (BATCH * NUM_TREES)   // 16384
#define WAVES_PERSIST 4096                // resident capacity at 4 waves/SIMD
#define ITERS (PAIRS_TOTAL / WAVES_PERSIST) // 4

__device__ __forceinline__ float sigmoidf_fast(float x) {
    return __fdividef(1.0f, 1.0f + __expf(-x));
}

__device__ __forceinline__ float sum8_sigmoid(const float4& a, const float4& b) {
    return sigmoidf_fast(a.x) + sigmoidf_fast(a.y) + sigmoidf_fast(a.z) + sigmoidf_fast(a.w) +
           sigmoidf_fast(b.x) + sigmoidf_fast(b.y) + sigmoidf_fast(b.z) + sigmoidf_fast(b.w);
}

__global__ __launch_bounds__(256) void ndt_kernel(const float* __restrict__ x,
                                                  float* __restrict__ out) {
    const int wave0 = (blockIdx.x * blockDim.x + threadIdx.x) >> 6; // persistent wave id
    const int lane = threadIdx.x & 63;
    const int e0 = lane * 8;

    // ---- Prologue: issue P1 (rows 0..5) loads for pair 0 ----
    float4 rs[6][2];
    {
        const float* b0 = x + (size_t)wave0 * (DEPTH * WIDTH) + e0;
#pragma unroll
        for (int i = 0; i < 6; ++i) {
            const float4* p = (const float4*)(b0 + i * WIDTH);
            rs[i][0] = p[0];
            rs[i][1] = p[1];
        }
    }

#pragma unroll
    for (int k = 0; k < ITERS; ++k) {
        const int pair = wave0 + k * WAVES_PERSIST;
        const float* bcur = x + (size_t)pair * (DEPTH * WIDTH) + e0;

        // ---- Issue P2 (rows 6..9) for current pair (12 P1 + 8 P2 in flight) ----
        float4 rv[4][2];
#pragma unroll
        for (int i = 0; i < 4; ++i) {
            const float4* p = (const float4*)(bcur + (6 + i) * WIDTH);
            rv[i][0] = p[0];
            rv[i][1] = p[1];
        }

        // ---- Consume P1: per-lane sigmoid sums (waits vmcnt(8), P2 stays in flight) ----
        float S[6];
#pragma unroll
        for (int i = 0; i < 6; ++i) S[i] = sum8_sigmoid(rs[i][0], rs[i][1]);

        // ---- Prefetch P1 of next pair into freed rs registers ----
        if (k + 1 < ITERS) {
            const float* bn = x + (size_t)(pair + WAVES_PERSIST) * (DEPTH * WIDTH) + e0;
#pragma unroll
            for (int i = 0; i < 6; ++i) {
                const float4* p = (const float4*)(bn + i * WIDTH);
                rs[i][0] = p[0];
                rs[i][1] = p[1];
            }
        }

        // ---- Consume P2: leaf-fold levels 9..6 (next pair's P1 covers HBM latency) ----
        // Level 9 (leaf sigmoids): v[0..7]
        float v[8];
        {
            const float* q = (const float*)&rv[3][0];
#pragma unroll
            for (int kk = 0; kk < 8; ++kk) v[kk] = sigmoidf_fast(q[kk]);
        }
        // Level 8: width-2 means, fold 8 -> 4
        {
            const float* q = (const float*)&rv[2][0];
#pragma unroll
            for (int kk = 0; kk < 4; ++kk) {
                float d = 0.5f * (sigmoidf_fast(q[2 * kk]) + sigmoidf_fast(q[2 * kk + 1]));
                v[kk] = (1.0f - d) * v[2 * kk] + d * v[2 * kk + 1];
            }
        }
        // Level 7: width-4 means, fold 4 -> 2
        {
            const float* q = (const float*)&rv[1][0];
#pragma unroll
            for (int kk = 0; kk < 2; ++kk) {
                float d = 0.25f * (sigmoidf_fast(q[4 * kk])     + sigmoidf_fast(q[4 * kk + 1]) +
                                   sigmoidf_fast(q[4 * kk + 2]) + sigmoidf_fast(q[4 * kk + 3]));
                v[kk] = (1.0f - d) * v[2 * kk] + d * v[2 * kk + 1];
            }
        }
        // Level 6: width-8 mean (whole lane), fold 2 -> 1
        float vv;
        {
            const float d = sum8_sigmoid(rv[0][0], rv[0][1]) * 0.125f;
            vv = (1.0f - d) * v[0] + d * v[1];
        }

        // ---- Butterfly fold, levels 5 down to 0 ----
#pragma unroll
        for (int step = 0; step < 6; ++step) {
            const int h = 1 << step;
            const int lvl = 5 - step;
#pragma unroll
            for (int i2 = 0; i2 <= lvl; ++i2) S[i2] += __shfl_xor(S[i2], h, 64);

            const float d = S[lvl] * (1.0f / (float)(16 << step)); // exact pow2 recip
            const float vo = __shfl_xor(vv, h, 64);
            const bool upper = ((lane >> step) & 1) != 0;
            const float v_even = upper ? vo : vv;
            const float v_odd  = upper ? vv : vo;
            vv = (1.0f - d) * v_even + d * v_odd;
        }

        if (lane == 0) out[pair] = vv;
    }
}

extern "C" void kernel_launch(void* const* d_in, const int* in_sizes, int n_in,
                              void* d_out, int out_size, void* d_ws, size_t ws_size,
                              hipStream_t stream) {
    const float* x = (const float*)d_in[0];
    float* out = (float*)d_out;
    const int block = 256;                              // 4 waves/block
    const int grid = WAVES_PERSIST / (block / 64);      // 1024 blocks
    ndt_kernel<<<grid, block, 0, stream>>>(x, out);
}